// Round 7
// baseline (790.634 us; speedup 1.0000x reference)
//
#include <hip/hip_runtime.h>
#include <hip/hip_fp16.h>
#include <cstdint>
#include <cstddef>

#define NNODES 100000
#define NEDGES 1600000
#define NGRAPH 1024
#define NB_SCAN ((NNODES + 255) / 256)   // 391
#define FILL_CHUNK 4096
#define FILL_NCHUNK ((NEDGES + FILL_CHUNK - 1) / FILL_CHUNK)  // 391
#define SHARD 12500                       // NNODES / 8

typedef __attribute__((ext_vector_type(8))) short short8;
typedef __attribute__((ext_vector_type(8))) unsigned short ushort8;
typedef __attribute__((ext_vector_type(4))) float f32x4;

__device__ inline float b2f(unsigned short u) {
  return __uint_as_float(((unsigned int)u) << 16);
}
__device__ inline unsigned short f2b(float f) {
  unsigned int x = __float_as_uint(f);
  x += 0x7fffu + ((x >> 16) & 1u);          // RNE
  return (unsigned short)(x >> 16);
}
// packed edge: (src << 15) | (fp16(weight) >> 1)   [weight >= 0 so sign bit = 0]
__device__ inline unsigned int pack_edge(int src, float w) {
  unsigned short hb = __half_as_ushort(__float2half_rn(w));
  return ((unsigned int)src << 15) | ((unsigned int)hb >> 1);
}
__device__ inline void unpack_edge(unsigned int p, int& src, float& w) {
  src = (int)(p >> 15);
  w = __half2float(__ushort_as_half((unsigned short)((p & 0x7fffu) << 1)));
}

// ---------------- weight prepack: W[HOUT][K] f32 -> bf16 MFMA-B order ----------------
__global__ __launch_bounds__(256) void prepack_kernel(
    const float* __restrict__ Wrel0, const float* __restrict__ Wroot0,
    const float* __restrict__ WrelR, const float* __restrict__ WrootR,
    const float* __restrict__ Wr1, unsigned short* __restrict__ dst)
{
  int g = blockIdx.x * 256 + threadIdx.x;
  if (g >= 15360) return;
  const float* src; int H, K, r; unsigned short* out;
  if (g < 1024)       { src = Wrel0;  H = 128; K = 64;  r = g;        out = dst + r * 8; }
  else if (g < 2048)  { src = Wroot0; H = 128; K = 64;  r = g - 1024; out = dst + 8192 + r * 8; }
  else if (g < 8192)  { int m = g - 2048; int l = m / 2048; r = m % 2048;
                        src = WrelR + l * 16384;  H = 128; K = 128;
                        out = dst + 16384 + l * 16384 + r * 8; }
  else if (g < 14336) { int m = g - 8192; int l = m / 2048; r = m % 2048;
                        src = WrootR + l * 16384; H = 128; K = 128;
                        out = dst + 65536 + l * 16384 + r * 8; }
  else                { src = Wr1;    H = 64;  K = 128; r = g - 14336; out = dst + 114688 + r * 8; }
  int n = r % H, k8 = r / H;
  const float* s = src + (size_t)n * K + k8 * 8;
#pragma unroll
  for (int j = 0; j < 8; j++) out[j] = f2b(s[j]);
}

// ---------------- x f32 -> bf16 ----------------
__global__ __launch_bounds__(256) void cvt_x_kernel(
    const float* __restrict__ x, unsigned short* __restrict__ xb)
{
  int i = blockIdx.x * 256 + threadIdx.x;
  if (i * 4 >= NNODES * 64) return;
  float4 v = *(const float4*)(x + i * 4);
  ushort4 o;
  o.x = f2b(v.x); o.y = f2b(v.y); o.z = f2b(v.z); o.w = f2b(v.w);
  *(ushort4*)(xb + i * 4) = o;
}

// ---------------- CSR build ----------------
__global__ __launch_bounds__(256) void hist_kernel(
    const int* __restrict__ ei, int* __restrict__ deg)
{
  int e = blockIdx.x * 256 + threadIdx.x;
  if (e < NEDGES) atomicAdd(&deg[__builtin_nontemporal_load(ei + NEDGES + e)], 1);
}

__global__ __launch_bounds__(256) void scan1_kernel(
    const int* __restrict__ deg, int* __restrict__ exloc, int* __restrict__ bsum)
{
  __shared__ int s[256];
  int i = blockIdx.x * 256 + threadIdx.x;
  int v = (i < NNODES) ? deg[i] : 0;
  s[threadIdx.x] = v;
  __syncthreads();
#pragma unroll
  for (int off = 1; off < 256; off <<= 1) {
    int t = (threadIdx.x >= off) ? s[threadIdx.x - off] : 0;
    __syncthreads();
    s[threadIdx.x] += t;
    __syncthreads();
  }
  if (i < NNODES) exloc[i] = s[threadIdx.x] - v;
  if (threadIdx.x == 255) bsum[blockIdx.x] = s[255];
}

__global__ __launch_bounds__(512) void scan2_kernel(int* __restrict__ bsum)
{
  __shared__ int s[512];
  int v = (threadIdx.x < NB_SCAN) ? bsum[threadIdx.x] : 0;
  s[threadIdx.x] = v;
  __syncthreads();
#pragma unroll
  for (int off = 1; off < 512; off <<= 1) {
    int t = (threadIdx.x >= off) ? s[threadIdx.x - off] : 0;
    __syncthreads();
    s[threadIdx.x] += t;
    __syncthreads();
  }
  if (threadIdx.x < NB_SCAN) bsum[threadIdx.x] = s[threadIdx.x] - v;
}

__global__ __launch_bounds__(256) void scan3_kernel(
    const int* __restrict__ exloc, const int* __restrict__ bsum,
    int* __restrict__ row_ptr, int* __restrict__ row_fill)
{
  int i = blockIdx.x * 256 + threadIdx.x;
  if (i < NNODES) {
    int v = exloc[i] + bsum[blockIdx.x];
    row_ptr[i] = v;
    row_fill[i] = v;
  }
  if (i == 0) row_ptr[NNODES] = NEDGES;
}

// XCD-sharded fill; streaming inputs read non-temporally so they do not evict
// the partially-filled epack write lines from L2.
__global__ __launch_bounds__(256) void fill_kernel(
    const int* __restrict__ ei, const float* __restrict__ ew,
    int* __restrict__ row_fill, unsigned int* __restrict__ epack)
{
  int chunk = blockIdx.x >> 3;
  int shard = blockIdx.x & 7;
  int base = chunk * FILL_CHUNK;
  for (int t = threadIdx.x; t < FILL_CHUNK; t += 256) {
    int e = base + t;
    if (e >= NEDGES) break;
    int d = __builtin_nontemporal_load(ei + NEDGES + e);
    if ((unsigned)d / SHARD == (unsigned)shard) {
      int src = __builtin_nontemporal_load(ei + e);
      float w = __builtin_nontemporal_load(ew + e);
      int p = atomicAdd(&row_fill[d], 1);
      epack[p] = pack_edge(src, w);
    }
  }
}

// ---------------- graph pointer (batch sorted) ----------------
__global__ __launch_bounds__(256) void gptr_kernel(
    const int* __restrict__ batch, int* __restrict__ gptr)
{
  int i = blockIdx.x * 256 + threadIdx.x;
  if (i >= NNODES) return;
  int b = batch[i];
  int bn = (i + 1 < NNODES) ? batch[i + 1] : NGRAPH;
  for (int g = b + 1; g <= bn; g++) gptr[g] = i + 1;
  if (i == 0) for (int g = 0; g <= b; g++) gptr[g] = 0;
}

// ---------------- fused layer: gather-agg into LDS, then dual MFMA ----------------
// out[n][:] = bias + agg(n) @ Wrel + xin[n] @ Wroot,  128 nodes per block.
// KDIM=128: ROWP=136 (272B rows: write stride 16B and A-frag stride 272B are both
//           2-way bank aliasing = free).  KDIM=64: ROWP=72.
template <int KDIM, int ROWP>
__global__ __launch_bounds__(256) void fused_layer_kernel(
    const int* __restrict__ row_ptr, const unsigned int* __restrict__ epack,
    const unsigned short* __restrict__ xin,
    const unsigned short* __restrict__ W_rel, const unsigned short* __restrict__ W_root,
    const float* __restrict__ bias, unsigned short* __restrict__ out)
{
  __shared__ unsigned short sAgg[128 * ROWP];
  const int wave = threadIdx.x >> 6, lane = threadIdx.x & 63;
  const int nbase = blockIdx.x * 128;

  // ---- phase 1: each wave aggregates 32 nodes into LDS ----
  if (KDIM == 128) {
    int q = lane >> 4, sl = lane & 15;
#pragma unroll 2
    for (int t = 0; t < 32; t++) {
      int nl = wave * 32 + t;
      int node = nbase + nl;
      int s = 0, e = 0;
      if (node < NNODES) { s = row_ptr[node]; e = row_ptr[node + 1]; }
      float acc[8];
#pragma unroll
      for (int j = 0; j < 8; j++) acc[j] = 0.f;
      for (int i = s + q; i < e; i += 16) {
        unsigned int p0 = epack[i];
        unsigned int p1 = (i + 4  < e) ? epack[i + 4]  : 0u;
        unsigned int p2 = (i + 8  < e) ? epack[i + 8]  : 0u;
        unsigned int p3 = (i + 12 < e) ? epack[i + 12] : 0u;
        int s0, s1, s2, s3; float w0, w1, w2, w3;
        unpack_edge(p0, s0, w0); unpack_edge(p1, s1, w1);
        unpack_edge(p2, s2, w2); unpack_edge(p3, s3, w3);
        ushort8 r0 = *(const ushort8*)(xin + (size_t)s0 * 128 + sl * 8);
        ushort8 r1 = *(const ushort8*)(xin + (size_t)s1 * 128 + sl * 8);
        ushort8 r2 = *(const ushort8*)(xin + (size_t)s2 * 128 + sl * 8);
        ushort8 r3 = *(const ushort8*)(xin + (size_t)s3 * 128 + sl * 8);
#pragma unroll
        for (int j = 0; j < 8; j++)
          acc[j] += w0 * b2f(r0[j]) + w1 * b2f(r1[j]) +
                    w2 * b2f(r2[j]) + w3 * b2f(r3[j]);
      }
#pragma unroll
      for (int j = 0; j < 8; j++) {
        acc[j] += __shfl_xor(acc[j], 16, 64);
        acc[j] += __shfl_xor(acc[j], 32, 64);
      }
      if (q == 0) {
        ushort8 o;
#pragma unroll
        for (int j = 0; j < 8; j++) o[j] = f2b(acc[j]);
        *(ushort8*)(sAgg + nl * ROWP + sl * 8) = o;
      }
    }
  } else {  // KDIM == 64
    int q = lane >> 3, sl = lane & 7;
#pragma unroll 2
    for (int t = 0; t < 32; t++) {
      int nl = wave * 32 + t;
      int node = nbase + nl;
      int s = 0, e = 0;
      if (node < NNODES) { s = row_ptr[node]; e = row_ptr[node + 1]; }
      float acc[8];
#pragma unroll
      for (int j = 0; j < 8; j++) acc[j] = 0.f;
      for (int i = s + q; i < e; i += 16) {
        unsigned int p0 = epack[i];
        unsigned int p1 = (i + 8 < e) ? epack[i + 8] : 0u;
        int s0, s1; float w0, w1;
        unpack_edge(p0, s0, w0); unpack_edge(p1, s1, w1);
        ushort8 r0 = *(const ushort8*)(xin + (size_t)s0 * 64 + sl * 8);
        ushort8 r1 = *(const ushort8*)(xin + (size_t)s1 * 64 + sl * 8);
#pragma unroll
        for (int j = 0; j < 8; j++)
          acc[j] += w0 * b2f(r0[j]) + w1 * b2f(r1[j]);
      }
#pragma unroll
      for (int j = 0; j < 8; j++) {
        acc[j] += __shfl_xor(acc[j], 8, 64);
        acc[j] += __shfl_xor(acc[j], 16, 64);
        acc[j] += __shfl_xor(acc[j], 32, 64);
      }
      if (q == 0) {
        ushort8 o;
#pragma unroll
        for (int j = 0; j < 8; j++) o[j] = f2b(acc[j]);
        *(ushort8*)(sAgg + nl * ROWP + sl * 8) = o;
      }
    }
  }
  __syncthreads();

  // ---- phase 2: MFMA. wave handles m-tiles {wave*2, wave*2+1} (HOUT=128) ----
  constexpr int NT2 = 8;
  constexpr int KC = KDIM / 32;
  const int quad = lane >> 4, l16 = lane & 15;

  f32x4 acc[2][NT2];
#pragma unroll
  for (int m = 0; m < 2; m++)
#pragma unroll
    for (int t = 0; t < NT2; t++) acc[m][t] = (f32x4){0.f, 0.f, 0.f, 0.f};

  int nodesg[2];
#pragma unroll
  for (int m = 0; m < 2; m++) {
    int nd = nbase + (wave * 2 + m) * 16 + l16;
    nodesg[m] = nd < NNODES ? nd : NNODES - 1;
  }

#pragma unroll
  for (int c = 0; c < KC; c++) {
    short8 bfr[NT2];
#pragma unroll
    for (int t = 0; t < NT2; t++)
      bfr[t] = *(const short8*)(W_rel + ((size_t)(c * 4 + quad) * 128 + t * 16 + l16) * 8);
#pragma unroll
    for (int m = 0; m < 2; m++) {
      short8 af = *(const short8*)(sAgg + ((wave * 2 + m) * 16 + l16) * ROWP + c * 32 + quad * 8);
#pragma unroll
      for (int t = 0; t < NT2; t++)
        acc[m][t] = __builtin_amdgcn_mfma_f32_16x16x32_bf16(af, bfr[t], acc[m][t], 0, 0, 0);
    }
#pragma unroll
    for (int t = 0; t < NT2; t++)
      bfr[t] = *(const short8*)(W_root + ((size_t)(c * 4 + quad) * 128 + t * 16 + l16) * 8);
#pragma unroll
    for (int m = 0; m < 2; m++) {
      short8 af = *(const short8*)(xin + (size_t)nodesg[m] * KDIM + c * 32 + quad * 8);
#pragma unroll
      for (int t = 0; t < NT2; t++)
        acc[m][t] = __builtin_amdgcn_mfma_f32_16x16x32_bf16(af, bfr[t], acc[m][t], 0, 0, 0);
    }
  }

#pragma unroll
  for (int m = 0; m < 2; m++) {
    int rowbase = nbase + (wave * 2 + m) * 16 + quad * 4;
#pragma unroll
    for (int t = 0; t < NT2; t++) {
      float b = bias[t * 16 + l16];
#pragma unroll
      for (int r = 0; r < 4; r++) {
        int nd = rowbase + r;
        if (nd < NNODES)
          out[(size_t)nd * 128 + t * 16 + l16] = f2b(acc[m][t][r] + b);
      }
    }
  }
}

// ---------------- LDS-free MFMA bf16 GEMM (readout layer 1) ----------------
template <int KDIM, int HOUT, int MT, bool RELU>
__global__ __launch_bounds__(256) void mfma_gemm(
    const unsigned short* __restrict__ A1, const unsigned short* __restrict__ W1,
    const float* __restrict__ bias, unsigned short* __restrict__ out)
{
  constexpr int NT2 = HOUT / 16;
  constexpr int KC = KDIM / 32;
  const int wave = threadIdx.x >> 6, lane = threadIdx.x & 63;
  const int quad = lane >> 4, l16 = lane & 15;
  const int n0 = (blockIdx.x * 4 + wave) * (MT * 16);

  f32x4 acc[MT][NT2];
#pragma unroll
  for (int m = 0; m < MT; m++)
#pragma unroll
    for (int t = 0; t < NT2; t++) acc[m][t] = (f32x4){0.f, 0.f, 0.f, 0.f};

  int nodes[MT];
#pragma unroll
  for (int m = 0; m < MT; m++) {
    int nd = n0 + m * 16 + l16;
    nodes[m] = nd < NNODES ? nd : NNODES - 1;
  }

#pragma unroll
  for (int c = 0; c < KC; c++) {
    short8 bfr[NT2];
#pragma unroll
    for (int t = 0; t < NT2; t++)
      bfr[t] = *(const short8*)(W1 + ((size_t)(c * 4 + quad) * HOUT + t * 16 + l16) * 8);
#pragma unroll
    for (int m = 0; m < MT; m++) {
      short8 af = *(const short8*)(A1 + (size_t)nodes[m] * KDIM + c * 32 + quad * 8);
#pragma unroll
      for (int t = 0; t < NT2; t++)
        acc[m][t] = __builtin_amdgcn_mfma_f32_16x16x32_bf16(af, bfr[t], acc[m][t], 0, 0, 0);
    }
  }

#pragma unroll
  for (int m = 0; m < MT; m++) {
    int rowbase = n0 + m * 16 + quad * 4;
#pragma unroll
    for (int t = 0; t < NT2; t++) {
      float b = bias[t * 16 + l16];
#pragma unroll
      for (int r = 0; r < 4; r++) {
        int nd = rowbase + r;
        if (nd < NNODES) {
          float v = acc[m][t][r] + b;
          if (RELU) v = fmaxf(v, 0.f);
          out[(size_t)nd * HOUT + t * 16 + l16] = f2b(v);
        }
      }
    }
  }
}

// ---------------- readout: per-graph block reduction ----------------
__global__ __launch_bounds__(256) void readout_reduce_kernel(
    const unsigned short* __restrict__ h, const float* __restrict__ Wr2,
    const float* __restrict__ br2, const int* __restrict__ gptr,
    float* __restrict__ out)
{
  __shared__ float wsum[4];
  int g = blockIdx.x;
  int s = gptr[g], e = gptr[g + 1];
  int wave = threadIdx.x >> 6, lane = threadIdx.x & 63;
  float w2 = Wr2[lane];
  float acc = 0.f;
  for (int n = s + wave; n < e; n += 4)
    acc += b2f(h[(size_t)n * 64 + lane]) * w2;
#pragma unroll
  for (int off = 32; off >= 1; off >>= 1) acc += __shfl_xor(acc, off, 64);
  if (lane == 0) wsum[wave] = acc;
  __syncthreads();
  if (threadIdx.x == 0) {
    float cnt = (float)(e - s);
    float sum = wsum[0] + wsum[1] + wsum[2] + wsum[3] + cnt * br2[0];
    out[g] = sum / fmaxf(cnt, 1.f);
  }
}

// ---------------- launch ----------------
extern "C" void kernel_launch(void* const* d_in, const int* in_sizes, int n_in,
                              void* d_out, int out_size, void* d_ws, size_t ws_size,
                              hipStream_t stream)
{
  const float* x      = (const float*)d_in[0];
  const int*   ei     = (const int*)d_in[1];
  const float* ew     = (const float*)d_in[2];
  const int*   batch  = (const int*)d_in[3];
  const float* Wroot0 = (const float*)d_in[4];
  const float* Wrel0  = (const float*)d_in[5];
  const float* b0     = (const float*)d_in[6];
  const float* WrootR = (const float*)d_in[7];
  const float* WrelR  = (const float*)d_in[8];
  const float* bR     = (const float*)d_in[9];
  const float* Wr1    = (const float*)d_in[10];
  const float* br1    = (const float*)d_in[11];
  const float* Wr2    = (const float*)d_in[12];
  const float* br2    = (const float*)d_in[13];

  char* ws = (char*)d_ws;
  unsigned short* wp   = (unsigned short*)ws;                 // 122880 bf16, pad to 131072
  unsigned short* xb   = wp + 131072;                         // N*64 bf16
  unsigned short* bufA = xb + (size_t)NNODES * 64;            // N*128 bf16
  unsigned short* bufB = bufA + (size_t)NNODES * 128;         // N*128 bf16
  unsigned short* hbuf = bufB + (size_t)NNODES * 128;         // N*64 bf16
  int*  deg      = (int*)(hbuf + (size_t)NNODES * 64);
  int*  exloc    = deg + NNODES;
  int*  row_ptr  = exloc + NNODES;
  int*  row_fill = row_ptr + NNODES + 2;
  int*  bsum     = row_fill + NNODES;
  int*  gptr     = bsum + 512;
  unsigned int* epack = (unsigned int*)(gptr + NGRAPH + 2);   // E uint = 6.4MB

  prepack_kernel<<<60, 256, 0, stream>>>(Wrel0, Wroot0, WrelR, WrootR, Wr1, wp);
  cvt_x_kernel<<<(NNODES * 64 / 4 + 255) / 256, 256, 0, stream>>>(x, xb);

  const unsigned short* pWrel0  = wp;
  const unsigned short* pWroot0 = wp + 8192;
  const unsigned short* pWrelR  = wp + 16384;
  const unsigned short* pWrootR = wp + 65536;
  const unsigned short* pWr1    = wp + 114688;

  // CSR (by dst) + graph ptr
  hipMemsetAsync(deg, 0, NNODES * sizeof(int), stream);
  hist_kernel<<<(NEDGES + 255) / 256, 256, 0, stream>>>(ei, deg);
  scan1_kernel<<<NB_SCAN, 256, 0, stream>>>(deg, exloc, bsum);
  scan2_kernel<<<1, 512, 0, stream>>>(bsum);
  scan3_kernel<<<NB_SCAN, 256, 0, stream>>>(exloc, bsum, row_ptr, row_fill);
  fill_kernel<<<FILL_NCHUNK * 8, 256, 0, stream>>>(ei, ew, row_fill, epack);
  gptr_kernel<<<(NNODES + 255) / 256, 256, 0, stream>>>(batch, gptr);

  const int NLB = (NNODES + 127) / 128;   // 782 blocks

  // layer 0: 64 -> 128 (fused agg+GEMM)
  fused_layer_kernel<64, 72><<<NLB, 256, 0, stream>>>(
      row_ptr, epack, xb, pWrel0, pWroot0, b0, bufB);

  // layers 1..3: 128 -> 128 (fused), ping-pong
  unsigned short* bufs[2] = { bufB, bufA };
  for (int l = 0; l < 3; l++) {
    unsigned short* in  = bufs[l & 1];
    unsigned short* out = bufs[(l & 1) ^ 1];
    fused_layer_kernel<128, 136><<<NLB, 256, 0, stream>>>(
        row_ptr, epack, in, pWrelR + l * 16384, pWrootR + l * 16384, bR + l * 128, out);
  }
  // y3 in bufA

  // readout
  mfma_gemm<128, 64, 4, true><<<(NNODES + 255) / 256, 256, 0, stream>>>(
      bufA, pWr1, br1, hbuf);
  readout_reduce_kernel<<<NGRAPH, 256, 0, stream>>>(hbuf, Wr2, br2, gptr, (float*)d_out);
}

// Round 9
// 620.806 us; speedup vs baseline: 1.2736x; 1.2736x over previous
//
#include <hip/hip_runtime.h>
#include <hip/hip_fp16.h>
#include <cstdint>
#include <cstddef>

#define NNODES 100000
#define NEDGES 1600000
#define NGRAPH 1024
#define NB_SCAN ((NNODES + 255) / 256)   // 391
#define FILL_CHUNK 4096
#define FILL_NCHUNK ((NEDGES + FILL_CHUNK - 1) / FILL_CHUNK)  // 391
#define SHARD 12500                       // NNODES / 8

typedef __attribute__((ext_vector_type(8))) short short8;
typedef __attribute__((ext_vector_type(8))) unsigned short ushort8;
typedef __attribute__((ext_vector_type(4))) float f32x4;

__device__ inline float b2f(unsigned short u) {
  return __uint_as_float(((unsigned int)u) << 16);
}
__device__ inline unsigned short f2b(float f) {
  unsigned int x = __float_as_uint(f);
  x += 0x7fffu + ((x >> 16) & 1u);          // RNE
  return (unsigned short)(x >> 16);
}
// packed edge: (src << 15) | (fp16(weight) >> 1)   [weight >= 0 so sign bit = 0]
__device__ inline unsigned int pack_edge(int src, float w) {
  unsigned short hb = __half_as_ushort(__float2half_rn(w));
  return ((unsigned int)src << 15) | ((unsigned int)hb >> 1);
}
__device__ inline void unpack_edge(unsigned int p, int& src, float& w) {
  src = (int)(p >> 15);
  w = __half2float(__ushort_as_half((unsigned short)((p & 0x7fffu) << 1)));
}

// ---------------- weight prepack: W[HOUT][K] f32 -> bf16 MFMA-B order ----------------
__global__ __launch_bounds__(256) void prepack_kernel(
    const float* __restrict__ Wrel0, const float* __restrict__ Wroot0,
    const float* __restrict__ WrelR, const float* __restrict__ WrootR,
    const float* __restrict__ Wr1, unsigned short* __restrict__ dst)
{
  int g = blockIdx.x * 256 + threadIdx.x;
  if (g >= 15360) return;
  const float* src; int H, K, r; unsigned short* out;
  if (g < 1024)       { src = Wrel0;  H = 128; K = 64;  r = g;        out = dst + r * 8; }
  else if (g < 2048)  { src = Wroot0; H = 128; K = 64;  r = g - 1024; out = dst + 8192 + r * 8; }
  else if (g < 8192)  { int m = g - 2048; int l = m / 2048; r = m % 2048;
                        src = WrelR + l * 16384;  H = 128; K = 128;
                        out = dst + 16384 + l * 16384 + r * 8; }
  else if (g < 14336) { int m = g - 8192; int l = m / 2048; r = m % 2048;
                        src = WrootR + l * 16384; H = 128; K = 128;
                        out = dst + 65536 + l * 16384 + r * 8; }
  else                { src = Wr1;    H = 64;  K = 128; r = g - 14336; out = dst + 114688 + r * 8; }
  int n = r % H, k8 = r / H;
  const float* s = src + (size_t)n * K + k8 * 8;
#pragma unroll
  for (int j = 0; j < 8; j++) out[j] = f2b(s[j]);
}

// ---------------- x f32 -> bf16 ----------------
__global__ __launch_bounds__(256) void cvt_x_kernel(
    const float* __restrict__ x, unsigned short* __restrict__ xb)
{
  int i = blockIdx.x * 256 + threadIdx.x;
  if (i * 4 >= NNODES * 64) return;
  f32x4 v = __builtin_nontemporal_load((const f32x4*)(x + i * 4));
  ushort4 o;
  o.x = f2b(v.x); o.y = f2b(v.y); o.z = f2b(v.z); o.w = f2b(v.w);
  *(ushort4*)(xb + i * 4) = o;
}

// ---------------- CSR build ----------------
__global__ __launch_bounds__(256) void hist_kernel(
    const int* __restrict__ ei, int* __restrict__ deg)
{
  int e = blockIdx.x * 256 + threadIdx.x;
  if (e < NEDGES) atomicAdd(&deg[__builtin_nontemporal_load(ei + NEDGES + e)], 1);
}

__global__ __launch_bounds__(256) void scan1_kernel(
    const int* __restrict__ deg, int* __restrict__ exloc, int* __restrict__ bsum)
{
  __shared__ int s[256];
  int i = blockIdx.x * 256 + threadIdx.x;
  int v = (i < NNODES) ? deg[i] : 0;
  s[threadIdx.x] = v;
  __syncthreads();
#pragma unroll
  for (int off = 1; off < 256; off <<= 1) {
    int t = (threadIdx.x >= off) ? s[threadIdx.x - off] : 0;
    __syncthreads();
    s[threadIdx.x] += t;
    __syncthreads();
  }
  if (i < NNODES) exloc[i] = s[threadIdx.x] - v;
  if (threadIdx.x == 255) bsum[blockIdx.x] = s[255];
}

__global__ __launch_bounds__(512) void scan2_kernel(int* __restrict__ bsum)
{
  __shared__ int s[512];
  int v = (threadIdx.x < NB_SCAN) ? bsum[threadIdx.x] : 0;
  s[threadIdx.x] = v;
  __syncthreads();
#pragma unroll
  for (int off = 1; off < 512; off <<= 1) {
    int t = (threadIdx.x >= off) ? s[threadIdx.x - off] : 0;
    __syncthreads();
    s[threadIdx.x] += t;
    __syncthreads();
  }
  if (threadIdx.x < NB_SCAN) bsum[threadIdx.x] = s[threadIdx.x] - v;
}

__global__ __launch_bounds__(256) void scan3_kernel(
    const int* __restrict__ exloc, const int* __restrict__ bsum,
    int* __restrict__ row_ptr, int* __restrict__ row_fill)
{
  int i = blockIdx.x * 256 + threadIdx.x;
  if (i < NNODES) {
    int v = exloc[i] + bsum[blockIdx.x];
    row_ptr[i] = v;
    row_fill[i] = v;
  }
  if (i == 0) row_ptr[NNODES] = NEDGES;
}

// XCD-sharded fill; streaming inputs read non-temporally so they do not evict
// the partially-filled epack write lines from the shard XCD's L2.
__global__ __launch_bounds__(256) void fill_kernel(
    const int* __restrict__ ei, const float* __restrict__ ew,
    int* __restrict__ row_fill, unsigned int* __restrict__ epack)
{
  int chunk = blockIdx.x >> 3;
  int shard = blockIdx.x & 7;
  int base = chunk * FILL_CHUNK;
  for (int t = threadIdx.x; t < FILL_CHUNK; t += 256) {
    int e = base + t;
    if (e >= NEDGES) break;
    int d = __builtin_nontemporal_load(ei + NEDGES + e);
    if ((unsigned)d / SHARD == (unsigned)shard) {
      int src = __builtin_nontemporal_load(ei + e);
      float w = __builtin_nontemporal_load(ew + e);
      int p = atomicAdd(&row_fill[d], 1);
      epack[p] = pack_edge(src, w);
    }
  }
}

// ---------------- graph pointer (batch sorted) ----------------
__global__ __launch_bounds__(256) void gptr_kernel(
    const int* __restrict__ batch, int* __restrict__ gptr)
{
  int i = blockIdx.x * 256 + threadIdx.x;
  if (i >= NNODES) return;
  int b = batch[i];
  int bn = (i + 1 < NNODES) ? batch[i + 1] : NGRAPH;
  for (int g = b + 1; g <= bn; g++) gptr[g] = i + 1;
  if (i == 0) for (int g = 0; g <= b; g++) gptr[g] = 0;
}

// ---------------- bf16 gather aggregation, high-MLP ----------------
// agg128: wave per node, quarter-split, 4-deep unroll -> 16 rows in flight/wave.
// epack is a read-once stream -> NT loads (keep L2 for x rows).
__global__ __launch_bounds__(256) void agg128_kernel(
    const int* __restrict__ row_ptr, const unsigned int* __restrict__ epack,
    const unsigned short* __restrict__ x, unsigned short* __restrict__ agg)
{
  int node = blockIdx.x * 4 + (threadIdx.x >> 6);
  int lane = threadIdx.x & 63;
  if (node >= NNODES) return;
  int q = lane >> 4, sl = lane & 15;
  int s = row_ptr[node], e = row_ptr[node + 1];
  float acc[8];
#pragma unroll
  for (int j = 0; j < 8; j++) acc[j] = 0.f;

  for (int i = s + q; i < e; i += 16) {
    unsigned int p0 = __builtin_nontemporal_load(epack + i);
    unsigned int p1 = (i + 4  < e) ? __builtin_nontemporal_load(epack + i + 4)  : 0u;
    unsigned int p2 = (i + 8  < e) ? __builtin_nontemporal_load(epack + i + 8)  : 0u;
    unsigned int p3 = (i + 12 < e) ? __builtin_nontemporal_load(epack + i + 12) : 0u;
    int s0, s1, s2, s3; float w0, w1, w2, w3;
    unpack_edge(p0, s0, w0);
    unpack_edge(p1, s1, w1);
    unpack_edge(p2, s2, w2);
    unpack_edge(p3, s3, w3);
    ushort8 r0 = *(const ushort8*)(x + (size_t)s0 * 128 + sl * 8);
    ushort8 r1 = *(const ushort8*)(x + (size_t)s1 * 128 + sl * 8);
    ushort8 r2 = *(const ushort8*)(x + (size_t)s2 * 128 + sl * 8);
    ushort8 r3 = *(const ushort8*)(x + (size_t)s3 * 128 + sl * 8);
#pragma unroll
    for (int j = 0; j < 8; j++)
      acc[j] += w0 * b2f(r0[j]) + w1 * b2f(r1[j]) +
                w2 * b2f(r2[j]) + w3 * b2f(r3[j]);
  }
#pragma unroll
  for (int j = 0; j < 8; j++) {
    acc[j] += __shfl_xor(acc[j], 16, 64);
    acc[j] += __shfl_xor(acc[j], 32, 64);
  }
  if (q == 0) {
    ushort8 o;
#pragma unroll
    for (int j = 0; j < 8; j++) o[j] = f2b(acc[j]);
    *(ushort8*)(agg + (size_t)node * 128 + sl * 8) = o;
  }
}

// agg64: wave per node, eighth-split, 2-deep unroll -> 16 rows in flight/wave.
__global__ __launch_bounds__(256) void agg64_kernel(
    const int* __restrict__ row_ptr, const unsigned int* __restrict__ epack,
    const unsigned short* __restrict__ x, unsigned short* __restrict__ agg)
{
  int node = blockIdx.x * 4 + (threadIdx.x >> 6);
  int lane = threadIdx.x & 63;
  if (node >= NNODES) return;
  int q = lane >> 3, sl = lane & 7;
  int s = row_ptr[node], e = row_ptr[node + 1];
  float acc[8];
#pragma unroll
  for (int j = 0; j < 8; j++) acc[j] = 0.f;

  for (int i = s + q; i < e; i += 16) {
    unsigned int p0 = __builtin_nontemporal_load(epack + i);
    unsigned int p1 = (i + 8 < e) ? __builtin_nontemporal_load(epack + i + 8) : 0u;
    int s0, s1; float w0, w1;
    unpack_edge(p0, s0, w0);
    unpack_edge(p1, s1, w1);
    ushort8 r0 = *(const ushort8*)(x + (size_t)s0 * 64 + sl * 8);
    ushort8 r1 = *(const ushort8*)(x + (size_t)s1 * 64 + sl * 8);
#pragma unroll
    for (int j = 0; j < 8; j++)
      acc[j] += w0 * b2f(r0[j]) + w1 * b2f(r1[j]);
  }
#pragma unroll
  for (int j = 0; j < 8; j++) {
    acc[j] += __shfl_xor(acc[j], 8, 64);
    acc[j] += __shfl_xor(acc[j], 16, 64);
    acc[j] += __shfl_xor(acc[j], 32, 64);
  }
  if (q == 0) {
    ushort8 o;
#pragma unroll
    for (int j = 0; j < 8; j++) o[j] = f2b(acc[j]);
    *(ushort8*)(agg + (size_t)node * 64 + sl * 8) = o;
  }
}

// ---------------- LDS-free MFMA bf16 GEMM ----------------
// A rows are read exactly once -> NT loads; W tiles are reused -> cached.
template <int KDIM, int HOUT, int MT, bool DUAL, bool RELU>
__global__ __launch_bounds__(256) void mfma_gemm(
    const unsigned short* __restrict__ A1, const unsigned short* __restrict__ W1,
    const unsigned short* __restrict__ A2, const unsigned short* __restrict__ W2,
    const float* __restrict__ bias, unsigned short* __restrict__ out)
{
  constexpr int NT2 = HOUT / 16;
  constexpr int KC = KDIM / 32;
  const int wave = threadIdx.x >> 6, lane = threadIdx.x & 63;
  const int quad = lane >> 4, l16 = lane & 15;
  const int n0 = (blockIdx.x * 4 + wave) * (MT * 16);

  f32x4 acc[MT][NT2];
#pragma unroll
  for (int m = 0; m < MT; m++)
#pragma unroll
    for (int t = 0; t < NT2; t++) acc[m][t] = (f32x4){0.f, 0.f, 0.f, 0.f};

  int nodes[MT];
#pragma unroll
  for (int m = 0; m < MT; m++) {
    int nd = n0 + m * 16 + l16;
    nodes[m] = nd < NNODES ? nd : NNODES - 1;
  }

#pragma unroll
  for (int c = 0; c < KC; c++) {
    short8 bfr[NT2];
#pragma unroll
    for (int t = 0; t < NT2; t++)
      bfr[t] = *(const short8*)(W1 + ((size_t)(c * 4 + quad) * HOUT + t * 16 + l16) * 8);
#pragma unroll
    for (int m = 0; m < MT; m++) {
      short8 af = __builtin_nontemporal_load(
          (const short8*)(A1 + (size_t)nodes[m] * KDIM + c * 32 + quad * 8));
#pragma unroll
      for (int t = 0; t < NT2; t++)
        acc[m][t] = __builtin_amdgcn_mfma_f32_16x16x32_bf16(af, bfr[t], acc[m][t], 0, 0, 0);
    }
    if (DUAL) {
#pragma unroll
      for (int t = 0; t < NT2; t++)
        bfr[t] = *(const short8*)(W2 + ((size_t)(c * 4 + quad) * HOUT + t * 16 + l16) * 8);
#pragma unroll
      for (int m = 0; m < MT; m++) {
        short8 af = __builtin_nontemporal_load(
            (const short8*)(A2 + (size_t)nodes[m] * KDIM + c * 32 + quad * 8));
#pragma unroll
        for (int t = 0; t < NT2; t++)
          acc[m][t] = __builtin_amdgcn_mfma_f32_16x16x32_bf16(af, bfr[t], acc[m][t], 0, 0, 0);
      }
    }
  }

#pragma unroll
  for (int m = 0; m < MT; m++) {
    int rowbase = n0 + m * 16 + quad * 4;
#pragma unroll
    for (int t = 0; t < NT2; t++) {
      float b = bias[t * 16 + l16];
#pragma unroll
      for (int r = 0; r < 4; r++) {
        int nd = rowbase + r;
        if (nd < NNODES) {
          float v = acc[m][t][r] + b;
          if (RELU) v = fmaxf(v, 0.f);
          out[(size_t)nd * HOUT + t * 16 + l16] = f2b(v);
        }
      }
    }
  }
}

// ---------------- readout: per-graph block reduction ----------------
__global__ __launch_bounds__(256) void readout_reduce_kernel(
    const unsigned short* __restrict__ h, const float* __restrict__ Wr2,
    const float* __restrict__ br2, const int* __restrict__ gptr,
    float* __restrict__ out)
{
  __shared__ float wsum[4];
  int g = blockIdx.x;
  int s = gptr[g], e = gptr[g + 1];
  int wave = threadIdx.x >> 6, lane = threadIdx.x & 63;
  float w2 = Wr2[lane];
  float acc = 0.f;
  for (int n = s + wave; n < e; n += 4)
    acc += b2f(__builtin_nontemporal_load(h + (size_t)n * 64 + lane)) * w2;
#pragma unroll
  for (int off = 32; off >= 1; off >>= 1) acc += __shfl_xor(acc, off, 64);
  if (lane == 0) wsum[wave] = acc;
  __syncthreads();
  if (threadIdx.x == 0) {
    float cnt = (float)(e - s);
    float sum = wsum[0] + wsum[1] + wsum[2] + wsum[3] + cnt * br2[0];
    out[g] = sum / fmaxf(cnt, 1.f);
  }
}

// ---------------- launch ----------------
extern "C" void kernel_launch(void* const* d_in, const int* in_sizes, int n_in,
                              void* d_out, int out_size, void* d_ws, size_t ws_size,
                              hipStream_t stream)
{
  const float* x      = (const float*)d_in[0];
  const int*   ei     = (const int*)d_in[1];
  const float* ew     = (const float*)d_in[2];
  const int*   batch  = (const int*)d_in[3];
  const float* Wroot0 = (const float*)d_in[4];
  const float* Wrel0  = (const float*)d_in[5];
  const float* b0     = (const float*)d_in[6];
  const float* WrootR = (const float*)d_in[7];
  const float* WrelR  = (const float*)d_in[8];
  const float* bR     = (const float*)d_in[9];
  const float* Wr1    = (const float*)d_in[10];
  const float* br1    = (const float*)d_in[11];
  const float* Wr2    = (const float*)d_in[12];
  const float* br2    = (const float*)d_in[13];

  char* ws = (char*)d_ws;
  unsigned short* wp   = (unsigned short*)ws;                 // 122880 bf16, pad to 131072
  unsigned short* xb   = wp + 131072;                         // N*64 bf16
  unsigned short* agg0 = xb + (size_t)NNODES * 64;            // N*64 bf16
  unsigned short* bufA = agg0 + (size_t)NNODES * 64;          // N*128 bf16
  unsigned short* bufB = bufA + (size_t)NNODES * 128;         // N*128 bf16
  unsigned short* hbuf = bufB + (size_t)NNODES * 128;         // N*64 bf16
  int*  deg      = (int*)(hbuf + (size_t)NNODES * 64);
  int*  exloc    = deg + NNODES;
  int*  row_ptr  = exloc + NNODES;
  int*  row_fill = row_ptr + NNODES + 2;
  int*  bsum     = row_fill + NNODES;
  int*  gptr     = bsum + 512;
  unsigned int* epack = (unsigned int*)(gptr + NGRAPH + 2);   // E uint = 6.4MB

  prepack_kernel<<<60, 256, 0, stream>>>(Wrel0, Wroot0, WrelR, WrootR, Wr1, wp);
  cvt_x_kernel<<<(NNODES * 64 / 4 + 255) / 256, 256, 0, stream>>>(x, xb);

  const unsigned short* pWrel0  = wp;
  const unsigned short* pWroot0 = wp + 8192;
  const unsigned short* pWrelR  = wp + 16384;
  const unsigned short* pWrootR = wp + 65536;
  const unsigned short* pWr1    = wp + 114688;

  // CSR (by dst) + graph ptr
  hipMemsetAsync(deg, 0, NNODES * sizeof(int), stream);
  hist_kernel<<<(NEDGES + 255) / 256, 256, 0, stream>>>(ei, deg);
  scan1_kernel<<<NB_SCAN, 256, 0, stream>>>(deg, exloc, bsum);
  scan2_kernel<<<1, 512, 0, stream>>>(bsum);
  scan3_kernel<<<NB_SCAN, 256, 0, stream>>>(exloc, bsum, row_ptr, row_fill);
  fill_kernel<<<FILL_NCHUNK * 8, 256, 0, stream>>>(ei, ew, row_fill, epack);
  gptr_kernel<<<(NNODES + 255) / 256, 256, 0, stream>>>(batch, gptr);

  // layer 0: 64 -> 128
  agg64_kernel<<<(NNODES + 3) / 4, 256, 0, stream>>>(row_ptr, epack, xb, agg0);
  mfma_gemm<64, 128, 2, true, false><<<(NNODES + 127) / 128, 256, 0, stream>>>(
      agg0, pWrel0, xb, pWroot0, b0, bufB);

  // layers 1..3: 128 -> 128
  unsigned short* bufs[2] = { bufB, bufA };
  for (int l = 0; l < 3; l++) {
    unsigned short* in  = bufs[l & 1];
    unsigned short* agg = bufs[(l & 1) ^ 1];
    agg128_kernel<<<(NNODES + 3) / 4, 256, 0, stream>>>(row_ptr, epack, in, agg);
    mfma_gemm<128, 128, 2, true, false><<<(NNODES + 127) / 128, 256, 0, stream>>>(
        agg, pWrelR + l * 16384, in, pWrootR + l * 16384, bR + l * 128, agg);
  }
  // y3 in bufA

  // readout
  mfma_gemm<128, 64, 4, false, true><<<(NNODES + 255) / 256, 256, 0, stream>>>(
      bufA, pWr1, nullptr, nullptr, br1, hbuf);
  readout_reduce_kernel<<<NGRAPH, 256, 0, stream>>>(hbuf, Wr2, br2, gptr, (float*)d_out);
}

// Round 10
// 606.072 us; speedup vs baseline: 1.3045x; 1.0243x over previous
//
#include <hip/hip_runtime.h>
#include <hip/hip_fp16.h>
#include <cstdint>
#include <cstddef>

#define NNODES 100000
#define NEDGES 1600000
#define NGRAPH 1024
#define NB_SCAN ((NNODES + 255) / 256)   // 391
#define FILL_CHUNK 4096
#define FILL_NCHUNK ((NEDGES + FILL_CHUNK - 1) / FILL_CHUNK)  // 391
#define SHARD 12500                       // NNODES / 8

typedef __attribute__((ext_vector_type(8))) short short8;
typedef __attribute__((ext_vector_type(8))) unsigned short ushort8;
typedef __attribute__((ext_vector_type(4))) float f32x4;

__device__ inline float b2f(unsigned short u) {
  return __uint_as_float(((unsigned int)u) << 16);
}
__device__ inline unsigned short f2b(float f) {
  unsigned int x = __float_as_uint(f);
  x += 0x7fffu + ((x >> 16) & 1u);          // RNE
  return (unsigned short)(x >> 16);
}
// packed edge: (src << 15) | (fp16(weight) >> 1)   [weight >= 0 so sign bit = 0]
__device__ inline unsigned int pack_edge(int src, float w) {
  unsigned short hb = __half_as_ushort(__float2half_rn(w));
  return ((unsigned int)src << 15) | ((unsigned int)hb >> 1);
}
__device__ inline void unpack_edge(unsigned int p, int& src, float& w) {
  src = (int)(p >> 15);
  w = __half2float(__ushort_as_half((unsigned short)((p & 0x7fffu) << 1)));
}

// ---------------- weight prepack: W[HOUT][K] f32 -> bf16 MFMA-B order ----------------
__global__ __launch_bounds__(256) void prepack_kernel(
    const float* __restrict__ Wrel0, const float* __restrict__ Wroot0,
    const float* __restrict__ WrelR, const float* __restrict__ WrootR,
    const float* __restrict__ Wr1, unsigned short* __restrict__ dst)
{
  int g = blockIdx.x * 256 + threadIdx.x;
  if (g >= 15360) return;
  const float* src; int H, K, r; unsigned short* out;
  if (g < 1024)       { src = Wrel0;  H = 128; K = 64;  r = g;        out = dst + r * 8; }
  else if (g < 2048)  { src = Wroot0; H = 128; K = 64;  r = g - 1024; out = dst + 8192 + r * 8; }
  else if (g < 8192)  { int m = g - 2048; int l = m / 2048; r = m % 2048;
                        src = WrelR + l * 16384;  H = 128; K = 128;
                        out = dst + 16384 + l * 16384 + r * 8; }
  else if (g < 14336) { int m = g - 8192; int l = m / 2048; r = m % 2048;
                        src = WrootR + l * 16384; H = 128; K = 128;
                        out = dst + 65536 + l * 16384 + r * 8; }
  else                { src = Wr1;    H = 64;  K = 128; r = g - 14336; out = dst + 114688 + r * 8; }
  int n = r % H, k8 = r / H;
  const float* s = src + (size_t)n * K + k8 * 8;
#pragma unroll
  for (int j = 0; j < 8; j++) out[j] = f2b(s[j]);
}

// ---------------- x f32 -> bf16 ----------------
__global__ __launch_bounds__(256) void cvt_x_kernel(
    const float* __restrict__ x, unsigned short* __restrict__ xb)
{
  int i = blockIdx.x * 256 + threadIdx.x;
  if (i * 4 >= NNODES * 64) return;
  f32x4 v = __builtin_nontemporal_load((const f32x4*)(x + i * 4));
  ushort4 o;
  o.x = f2b(v.x); o.y = f2b(v.y); o.z = f2b(v.z); o.w = f2b(v.w);
  *(ushort4*)(xb + i * 4) = o;
}

// ---------------- CSR build ----------------
__global__ __launch_bounds__(256) void hist_kernel(
    const int* __restrict__ ei, int* __restrict__ deg)
{
  int e = blockIdx.x * 256 + threadIdx.x;
  if (e < NEDGES) atomicAdd(&deg[__builtin_nontemporal_load(ei + NEDGES + e)], 1);
}

__global__ __launch_bounds__(256) void scan1_kernel(
    const int* __restrict__ deg, int* __restrict__ exloc, int* __restrict__ bsum)
{
  __shared__ int s[256];
  int i = blockIdx.x * 256 + threadIdx.x;
  int v = (i < NNODES) ? deg[i] : 0;
  s[threadIdx.x] = v;
  __syncthreads();
#pragma unroll
  for (int off = 1; off < 256; off <<= 1) {
    int t = (threadIdx.x >= off) ? s[threadIdx.x - off] : 0;
    __syncthreads();
    s[threadIdx.x] += t;
    __syncthreads();
  }
  if (i < NNODES) exloc[i] = s[threadIdx.x] - v;
  if (threadIdx.x == 255) bsum[blockIdx.x] = s[255];
}

__global__ __launch_bounds__(512) void scan2_kernel(int* __restrict__ bsum)
{
  __shared__ int s[512];
  int v = (threadIdx.x < NB_SCAN) ? bsum[threadIdx.x] : 0;
  s[threadIdx.x] = v;
  __syncthreads();
#pragma unroll
  for (int off = 1; off < 512; off <<= 1) {
    int t = (threadIdx.x >= off) ? s[threadIdx.x - off] : 0;
    __syncthreads();
    s[threadIdx.x] += t;
    __syncthreads();
  }
  if (threadIdx.x < NB_SCAN) bsum[threadIdx.x] = s[threadIdx.x] - v;
}

__global__ __launch_bounds__(256) void scan3_kernel(
    const int* __restrict__ exloc, const int* __restrict__ bsum,
    int* __restrict__ row_ptr, int* __restrict__ row_fill)
{
  int i = blockIdx.x * 256 + threadIdx.x;
  if (i < NNODES) {
    int v = exloc[i] + bsum[blockIdx.x];
    row_ptr[i] = v;
    row_fill[i] = v;
  }
  if (i == 0) row_ptr[NNODES] = NEDGES;
}

// XCD-sharded fill; streaming inputs read non-temporally so they do not evict
// the partially-filled epack write lines from the shard XCD's L2.
__global__ __launch_bounds__(256) void fill_kernel(
    const int* __restrict__ ei, const float* __restrict__ ew,
    int* __restrict__ row_fill, unsigned int* __restrict__ epack)
{
  int chunk = blockIdx.x >> 3;
  int shard = blockIdx.x & 7;
  int base = chunk * FILL_CHUNK;
  for (int t = threadIdx.x; t < FILL_CHUNK; t += 256) {
    int e = base + t;
    if (e >= NEDGES) break;
    int d = __builtin_nontemporal_load(ei + NEDGES + e);
    if ((unsigned)d / SHARD == (unsigned)shard) {
      int src = __builtin_nontemporal_load(ei + e);
      float w = __builtin_nontemporal_load(ew + e);
      int p = atomicAdd(&row_fill[d], 1);
      epack[p] = pack_edge(src, w);
    }
  }
}

// ---------------- graph pointer (batch sorted) ----------------
__global__ __launch_bounds__(256) void gptr_kernel(
    const int* __restrict__ batch, int* __restrict__ gptr)
{
  int i = blockIdx.x * 256 + threadIdx.x;
  if (i >= NNODES) return;
  int b = batch[i];
  int bn = (i + 1 < NNODES) ? batch[i + 1] : NGRAPH;
  for (int g = b + 1; g <= bn; g++) gptr[g] = i + 1;
  if (i == 0) for (int g = 0; g <= b; g++) gptr[g] = 0;
}

// ---------------- bf16 gather aggregation, high-MLP (R6 bodies) ----------------
__global__ __launch_bounds__(256) void agg128_kernel(
    const int* __restrict__ row_ptr, const unsigned int* __restrict__ epack,
    const unsigned short* __restrict__ x, unsigned short* __restrict__ agg)
{
  int node = blockIdx.x * 4 + (threadIdx.x >> 6);
  int lane = threadIdx.x & 63;
  if (node >= NNODES) return;
  int q = lane >> 4, sl = lane & 15;
  int s = row_ptr[node], e = row_ptr[node + 1];
  float acc[8];
#pragma unroll
  for (int j = 0; j < 8; j++) acc[j] = 0.f;

  for (int i = s + q; i < e; i += 16) {
    unsigned int p0 = epack[i];
    unsigned int p1 = (i + 4  < e) ? epack[i + 4]  : 0u;
    unsigned int p2 = (i + 8  < e) ? epack[i + 8]  : 0u;
    unsigned int p3 = (i + 12 < e) ? epack[i + 12] : 0u;
    int s0, s1, s2, s3; float w0, w1, w2, w3;
    unpack_edge(p0, s0, w0);
    unpack_edge(p1, s1, w1);
    unpack_edge(p2, s2, w2);
    unpack_edge(p3, s3, w3);
    ushort8 r0 = *(const ushort8*)(x + (size_t)s0 * 128 + sl * 8);
    ushort8 r1 = *(const ushort8*)(x + (size_t)s1 * 128 + sl * 8);
    ushort8 r2 = *(const ushort8*)(x + (size_t)s2 * 128 + sl * 8);
    ushort8 r3 = *(const ushort8*)(x + (size_t)s3 * 128 + sl * 8);
#pragma unroll
    for (int j = 0; j < 8; j++)
      acc[j] += w0 * b2f(r0[j]) + w1 * b2f(r1[j]) +
                w2 * b2f(r2[j]) + w3 * b2f(r3[j]);
  }
#pragma unroll
  for (int j = 0; j < 8; j++) {
    acc[j] += __shfl_xor(acc[j], 16, 64);
    acc[j] += __shfl_xor(acc[j], 32, 64);
  }
  if (q == 0) {
    ushort8 o;
#pragma unroll
    for (int j = 0; j < 8; j++) o[j] = f2b(acc[j]);
    *(ushort8*)(agg + (size_t)node * 128 + sl * 8) = o;
  }
}

__global__ __launch_bounds__(256) void agg64_kernel(
    const int* __restrict__ row_ptr, const unsigned int* __restrict__ epack,
    const unsigned short* __restrict__ x, unsigned short* __restrict__ agg)
{
  int node = blockIdx.x * 4 + (threadIdx.x >> 6);
  int lane = threadIdx.x & 63;
  if (node >= NNODES) return;
  int q = lane >> 3, sl = lane & 7;
  int s = row_ptr[node], e = row_ptr[node + 1];
  float acc[8];
#pragma unroll
  for (int j = 0; j < 8; j++) acc[j] = 0.f;

  for (int i = s + q; i < e; i += 16) {
    unsigned int p0 = epack[i];
    unsigned int p1 = (i + 8 < e) ? epack[i + 8] : 0u;
    int s0, s1; float w0, w1;
    unpack_edge(p0, s0, w0);
    unpack_edge(p1, s1, w1);
    ushort8 r0 = *(const ushort8*)(x + (size_t)s0 * 64 + sl * 8);
    ushort8 r1 = *(const ushort8*)(x + (size_t)s1 * 64 + sl * 8);
#pragma unroll
    for (int j = 0; j < 8; j++)
      acc[j] += w0 * b2f(r0[j]) + w1 * b2f(r1[j]);
  }
#pragma unroll
  for (int j = 0; j < 8; j++) {
    acc[j] += __shfl_xor(acc[j], 8, 64);
    acc[j] += __shfl_xor(acc[j], 16, 64);
    acc[j] += __shfl_xor(acc[j], 32, 64);
  }
  if (q == 0) {
    ushort8 o;
#pragma unroll
    for (int j = 0; j < 8; j++) o[j] = f2b(acc[j]);
    *(ushort8*)(agg + (size_t)node * 64 + sl * 8) = o;
  }
}

// ---------------- LDS-free MFMA bf16 GEMM ----------------
// MT=1: 64 nodes/block -> 1563 blocks -> ~6 blocks/CU (24 waves) for latency hiding.
template <int KDIM, int HOUT, int MT, bool DUAL, bool RELU>
__global__ __launch_bounds__(256) void mfma_gemm(
    const unsigned short* __restrict__ A1, const unsigned short* __restrict__ W1,
    const unsigned short* __restrict__ A2, const unsigned short* __restrict__ W2,
    const float* __restrict__ bias, unsigned short* __restrict__ out)
{
  constexpr int NT2 = HOUT / 16;
  constexpr int KC = KDIM / 32;
  const int wave = threadIdx.x >> 6, lane = threadIdx.x & 63;
  const int quad = lane >> 4, l16 = lane & 15;
  const int n0 = (blockIdx.x * 4 + wave) * (MT * 16);

  f32x4 acc[MT][NT2];
#pragma unroll
  for (int m = 0; m < MT; m++)
#pragma unroll
    for (int t = 0; t < NT2; t++) acc[m][t] = (f32x4){0.f, 0.f, 0.f, 0.f};

  int nodes[MT];
#pragma unroll
  for (int m = 0; m < MT; m++) {
    int nd = n0 + m * 16 + l16;
    nodes[m] = nd < NNODES ? nd : NNODES - 1;
  }

#pragma unroll
  for (int c = 0; c < KC; c++) {
    short8 bfr[NT2];
#pragma unroll
    for (int t = 0; t < NT2; t++)
      bfr[t] = *(const short8*)(W1 + ((size_t)(c * 4 + quad) * HOUT + t * 16 + l16) * 8);
#pragma unroll
    for (int m = 0; m < MT; m++) {
      short8 af = *(const short8*)(A1 + (size_t)nodes[m] * KDIM + c * 32 + quad * 8);
#pragma unroll
      for (int t = 0; t < NT2; t++)
        acc[m][t] = __builtin_amdgcn_mfma_f32_16x16x32_bf16(af, bfr[t], acc[m][t], 0, 0, 0);
    }
    if (DUAL) {
#pragma unroll
      for (int t = 0; t < NT2; t++)
        bfr[t] = *(const short8*)(W2 + ((size_t)(c * 4 + quad) * HOUT + t * 16 + l16) * 8);
#pragma unroll
      for (int m = 0; m < MT; m++) {
        short8 af = *(const short8*)(A2 + (size_t)nodes[m] * KDIM + c * 32 + quad * 8);
#pragma unroll
        for (int t = 0; t < NT2; t++)
          acc[m][t] = __builtin_amdgcn_mfma_f32_16x16x32_bf16(af, bfr[t], acc[m][t], 0, 0, 0);
      }
    }
  }

#pragma unroll
  for (int m = 0; m < MT; m++) {
    int rowbase = n0 + m * 16 + quad * 4;
#pragma unroll
    for (int t = 0; t < NT2; t++) {
      float b = bias[t * 16 + l16];
#pragma unroll
      for (int r = 0; r < 4; r++) {
        int nd = rowbase + r;
        if (nd < NNODES) {
          float v = acc[m][t][r] + b;
          if (RELU) v = fmaxf(v, 0.f);
          out[(size_t)nd * HOUT + t * 16 + l16] = f2b(v);
        }
      }
    }
  }
}

// ---------------- readout: per-graph block reduction ----------------
__global__ __launch_bounds__(256) void readout_reduce_kernel(
    const unsigned short* __restrict__ h, const float* __restrict__ Wr2,
    const float* __restrict__ br2, const int* __restrict__ gptr,
    float* __restrict__ out)
{
  __shared__ float wsum[4];
  int g = blockIdx.x;
  int s = gptr[g], e = gptr[g + 1];
  int wave = threadIdx.x >> 6, lane = threadIdx.x & 63;
  float w2 = Wr2[lane];
  float acc = 0.f;
  for (int n = s + wave; n < e; n += 4)
    acc += b2f(h[(size_t)n * 64 + lane]) * w2;
#pragma unroll
  for (int off = 32; off >= 1; off >>= 1) acc += __shfl_xor(acc, off, 64);
  if (lane == 0) wsum[wave] = acc;
  __syncthreads();
  if (threadIdx.x == 0) {
    float cnt = (float)(e - s);
    float sum = wsum[0] + wsum[1] + wsum[2] + wsum[3] + cnt * br2[0];
    out[g] = sum / fmaxf(cnt, 1.f);
  }
}

// ---------------- launch ----------------
extern "C" void kernel_launch(void* const* d_in, const int* in_sizes, int n_in,
                              void* d_out, int out_size, void* d_ws, size_t ws_size,
                              hipStream_t stream)
{
  const float* x      = (const float*)d_in[0];
  const int*   ei     = (const int*)d_in[1];
  const float* ew     = (const float*)d_in[2];
  const int*   batch  = (const int*)d_in[3];
  const float* Wroot0 = (const float*)d_in[4];
  const float* Wrel0  = (const float*)d_in[5];
  const float* b0     = (const float*)d_in[6];
  const float* WrootR = (const float*)d_in[7];
  const float* WrelR  = (const float*)d_in[8];
  const float* bR     = (const float*)d_in[9];
  const float* Wr1    = (const float*)d_in[10];
  const float* br1    = (const float*)d_in[11];
  const float* Wr2    = (const float*)d_in[12];
  const float* br2    = (const float*)d_in[13];

  char* ws = (char*)d_ws;
  unsigned short* wp   = (unsigned short*)ws;                 // 122880 bf16, pad to 131072
  unsigned short* xb   = wp + 131072;                         // N*64 bf16
  unsigned short* agg0 = xb + (size_t)NNODES * 64;            // N*64 bf16
  unsigned short* bufA = agg0 + (size_t)NNODES * 64;          // N*128 bf16
  unsigned short* bufB = bufA + (size_t)NNODES * 128;         // N*128 bf16
  unsigned short* hbuf = bufB + (size_t)NNODES * 128;         // N*64 bf16
  int*  deg      = (int*)(hbuf + (size_t)NNODES * 64);
  int*  exloc    = deg + NNODES;
  int*  row_ptr  = exloc + NNODES;
  int*  row_fill = row_ptr + NNODES + 2;
  int*  bsum     = row_fill + NNODES;
  int*  gptr     = bsum + 512;
  unsigned int* epack = (unsigned int*)(gptr + NGRAPH + 2);   // E uint = 6.4MB

  prepack_kernel<<<60, 256, 0, stream>>>(Wrel0, Wroot0, WrelR, WrootR, Wr1, wp);
  cvt_x_kernel<<<(NNODES * 64 / 4 + 255) / 256, 256, 0, stream>>>(x, xb);

  const unsigned short* pWrel0  = wp;
  const unsigned short* pWroot0 = wp + 8192;
  const unsigned short* pWrelR  = wp + 16384;
  const unsigned short* pWrootR = wp + 65536;
  const unsigned short* pWr1    = wp + 114688;

  // CSR (by dst) + graph ptr
  hipMemsetAsync(deg, 0, NNODES * sizeof(int), stream);
  hist_kernel<<<(NEDGES + 255) / 256, 256, 0, stream>>>(ei, deg);
  scan1_kernel<<<NB_SCAN, 256, 0, stream>>>(deg, exloc, bsum);
  scan2_kernel<<<1, 512, 0, stream>>>(bsum);
  scan3_kernel<<<NB_SCAN, 256, 0, stream>>>(exloc, bsum, row_ptr, row_fill);
  fill_kernel<<<FILL_NCHUNK * 8, 256, 0, stream>>>(ei, ew, row_fill, epack);
  gptr_kernel<<<(NNODES + 255) / 256, 256, 0, stream>>>(batch, gptr);

  // layer 0: 64 -> 128
  agg64_kernel<<<(NNODES + 3) / 4, 256, 0, stream>>>(row_ptr, epack, xb, agg0);
  mfma_gemm<64, 128, 1, true, false><<<(NNODES + 63) / 64, 256, 0, stream>>>(
      agg0, pWrel0, xb, pWroot0, b0, bufB);

  // layers 1..3: 128 -> 128
  unsigned short* bufs[2] = { bufB, bufA };
  for (int l = 0; l < 3; l++) {
    unsigned short* in  = bufs[l & 1];
    unsigned short* agg = bufs[(l & 1) ^ 1];
    agg128_kernel<<<(NNODES + 3) / 4, 256, 0, stream>>>(row_ptr, epack, in, agg);
    mfma_gemm<128, 128, 1, true, false><<<(NNODES + 63) / 64, 256, 0, stream>>>(
        agg, pWrelR + l * 16384, in, pWrootR + l * 16384, bR + l * 128, agg);
  }
  // y3 in bufA

  // readout
  mfma_gemm<128, 64, 1, false, true><<<(NNODES + 63) / 64, 256, 0, stream>>>(
      bufA, pWr1, nullptr, nullptr, br1, hbuf);
  readout_reduce_kernel<<<NGRAPH, 256, 0, stream>>>(hbuf, Wr2, br2, gptr, (float*)d_out);
}